// Round 14
// baseline (855.150 us; speedup 1.0000x reference)
//
#include <hip/hip_runtime.h>
#include <hip/hip_bf16.h>
#include <math.h>

// ---- problem constants ----
#define Bv 2
#define Tv 2048
#define Dv 1024
#define Hv 16
#define Ev 8
#define Kv 2
#define Fv 4096
#define HDv 64
#define NT 4096   // B*T tokens
#define MAXTILES 72

typedef __attribute__((ext_vector_type(8))) short short8;
typedef __attribute__((ext_vector_type(4))) float f32x4;

__device__ __forceinline__ short f2bf(float f) {
  unsigned u = __builtin_bit_cast(unsigned, f);
  u += 0x7fffu + ((u >> 16) & 1u);
  return (short)(u >> 16);
}
__device__ __forceinline__ float bf2f(short s) {
  unsigned u = ((unsigned)(unsigned short)s) << 16;
  return __builtin_bit_cast(float, u);
}
__device__ __forceinline__ float wredsum(float s) {
  #pragma unroll
  for (int off = 32; off; off >>= 1) s += __shfl_down(s, off, 64);
  return s;
}
// async global->LDS, 16B per lane; LDS dest = wave-uniform base + lane*16
__device__ __forceinline__ void gl_lds16(const short* g, short* l) {
  __builtin_amdgcn_global_load_lds(
      (const __attribute__((address_space(1))) unsigned int*)g,
      (__attribute__((address_space(3))) unsigned int*)l, 16, 0, 0);
}

// ---------------- transpose + fp32->bf16 convert ----------------
__global__ __launch_bounds__(256) void transpose_cvt(const float* __restrict__ in,
                                                     short* __restrict__ out,
                                                     int Kd, int Nd) {
  __shared__ float tile[64][65];
  const float* inb = in + (size_t)blockIdx.z * Kd * Nd;
  short* outb = out + (size_t)blockIdx.z * Kd * Nd;
  const int k0 = blockIdx.x * 64, n0 = blockIdx.y * 64;
  const int rr = threadIdx.x >> 4, cc = (threadIdx.x & 15) * 4;
  #pragma unroll
  for (int i = 0; i < 4; i++) {
    int r = rr + i * 16;
    f32x4 v = *(const f32x4*)(inb + (size_t)(k0 + r) * Nd + n0 + cc);
    tile[r][cc] = v[0]; tile[r][cc + 1] = v[1];
    tile[r][cc + 2] = v[2]; tile[r][cc + 3] = v[3];
  }
  __syncthreads();
  #pragma unroll
  for (int i = 0; i < 2; i++) {
    int e = threadIdx.x + i * 256;
    int n = e >> 3, c = (e & 7) * 8;
    short8 v;
    #pragma unroll
    for (int j = 0; j < 8; j++) v[j] = f2bf(tile[c + j][n]);
    *(short8*)(outb + (size_t)(n0 + n) * Kd + k0 + c) = v;
  }
}

// ---------------- V pre-transpose ----------------
__global__ __launch_bounds__(256) void vtrans_kernel(const short* __restrict__ qkv,
                                                     short* __restrict__ vT) {
  __shared__ short tile[64][72];
  const int t0 = blockIdx.x * 64;
  const int bh = blockIdx.y;
  const int b = bh >> 4, h = bh & 15;
  #pragma unroll
  for (int i = 0; i < 2; i++) {
    int e = threadIdx.x + i * 256;
    int r = e >> 3, c = (e & 7) * 8;
    short8 v = *(const short8*)(qkv + (size_t)(b * Tv + t0 + r) * 3072 + 2048 + h * 64 + c);
    *(short8*)(&tile[r][c]) = v;
  }
  __syncthreads();
  #pragma unroll
  for (int i = 0; i < 2; i++) {
    int e = threadIdx.x + i * 256;
    int d = e >> 3, c = (e & 7) * 8;
    short8 v;
    #pragma unroll
    for (int j = 0; j < 8; j++) v[j] = tile[c + j][d];
    *(short8*)(vT + ((size_t)bh * 64 + d) * Tv + t0 + c) = v;
  }
}

// ---------------- LayerNorm ----------------
__global__ __launch_bounds__(256) void ln_kernel(const float* __restrict__ in,
                                                 const float* __restrict__ w,
                                                 float* __restrict__ outf,
                                                 short* __restrict__ outb) {
  int t = blockIdx.x;
  int tid = threadIdx.x;
  const float* row = in + (size_t)t * Dv;
  float v[4]; float s = 0.f;
  #pragma unroll
  for (int i = 0; i < 4; i++) { v[i] = row[tid + i * 256]; s += v[i]; }
  s = wredsum(s);
  __shared__ float red[4], red2[4];
  int wv = tid >> 6, ln = tid & 63;
  if (ln == 0) red[wv] = s;
  __syncthreads();
  float mu = (red[0] + red[1] + red[2] + red[3]) * (1.f / Dv);
  float vs = 0.f;
  #pragma unroll
  for (int i = 0; i < 4; i++) { float d = v[i] - mu; vs += d * d; }
  vs = wredsum(vs);
  if (ln == 0) red2[wv] = vs;
  __syncthreads();
  float var = (red2[0] + red2[1] + red2[2] + red2[3]) * (1.f / Dv);
  float inv = rsqrtf(var + 1e-5f);
  #pragma unroll
  for (int i = 0; i < 4; i++) {
    int d = tid + i * 256;
    float o = (v[i] - mu) * inv * w[d];
    if (outf) outf[(size_t)t * Dv + d] = o;
    if (outb) outb[(size_t)t * Dv + d] = f2bf(o);
  }
}

enum { EPI_BF16 = 0, EPI_RESID = 1, EPI_GELU = 2 };

// ---------------- depth-2 pipelined m97 GEMM: 128x128 tile, BK=32, 4 waves ----------------
// A[M][KC] bf16 x Bt[N][KC] bf16. global_load_lds width=16, linear LDS.
// 3 LDS buffers; during tile t we stage tile t+2 (issue-to-wait distance = 2 tiles).
// Per tile: STAGE(t+2) + COMPUTE(t) + vmcnt(4) [retires exactly tile t+1's loads,
// never drains to 0 until tail] + ONE s_barrier. Race-free: stage target is always
// 2 buffers ahead (mod 3); ds_reads execute at LDS at issue, pre-barrier.
// T1 XCD-chunk swizzle (nwg % 8 == 0 by construction).
template<int EPI, bool MOE, bool INDIRECT, int KC>
__global__ __launch_bounds__(256) void gemm_lds(
    const short* __restrict__ A, const short* __restrict__ Bt,
    short* __restrict__ Cb, float* __restrict__ Cf,
    const float* __restrict__ resid,
    const int* __restrict__ perm, const int* __restrict__ tiles,
    int M, int N) {
  __shared__ short As[3][128][32];   // 8 KB each; linear (global_load_lds dest)
  __shared__ short Bs[3][128][32];
  const int nwg = gridDim.x * gridDim.y;
  const int orig = blockIdx.y * gridDim.x + blockIdx.x;
  const int cpx = nwg >> 3;
  const int wgid = (orig & 7) * cpx + (orig >> 3);
  const int mt = wgid % gridDim.x;
  const int npan = wgid / gridDim.x;

  int row0, row_end;
  const short* Bp = Bt;
  if (MOE) {
    int ntile = tiles[0];
    if (mt >= ntile) return;
    int e   = tiles[1 + mt * 3];
    row0    = tiles[2 + mt * 3];
    row_end = tiles[3 + mt * 3];
    Bp = Bt + (size_t)e * KC * N;
  } else {
    row0 = mt * 128; row_end = M;
  }
  const int nbase = npan * 128;
  const int tid = threadIdx.x;
  const int lane = tid & 63;
  const int w = tid >> 6;
  const int wm = (w >> 1) * 64, wn = (w & 1) * 64;
  const int lr = lane & 15, lk = (lane >> 4) * 8;

  // staging: one wave-load = 64 lanes x 16B = 16 rows of 64B (32 bf16)
  const int lrow = lane >> 2, lcol = (lane & 3) * 8;
  const short* asrc[2];
  const short* bsrc[2];
  #pragma unroll
  for (int i = 0; i < 2; i++) {
    int grow = row0 + w * 16 + i * 64 + lrow;
    if (MOE) grow = min(grow, row_end - 1);
    int arow = INDIRECT ? perm[grow] : grow;
    asrc[i] = A + (size_t)arow * KC + lcol;
    bsrc[i] = Bp + (size_t)(nbase + w * 16 + i * 64 + lrow) * KC + lcol;
  }

  // stage one K-tile (4 gl_lds/thread) into buffer (Ad,Bd) at element offset k0
  auto STAGE = [&](short (*Ad)[32], short (*Bd)[32], int k0) {
    gl_lds16(asrc[0] + k0, &Ad[w * 16][0]);
    gl_lds16(bsrc[0] + k0, &Bd[w * 16][0]);
    gl_lds16(asrc[1] + k0, &Ad[w * 16 + 64][0]);
    gl_lds16(bsrc[1] + k0, &Bd[w * 16 + 64][0]);
  };

  f32x4 acc[4][4];
  #pragma unroll
  for (int m = 0; m < 4; m++)
    #pragma unroll
    for (int n = 0; n < 4; n++) acc[m][n] = (f32x4)0.0f;

  auto COMPUTE = [&](short (*Ab)[32], short (*Bb)[32]) {
    short8 af[4], bfr[4];
    #pragma unroll
    for (int m = 0; m < 4; m++) af[m] = *(const short8*)(&Ab[wm + m * 16 + lr][lk]);
    #pragma unroll
    for (int n = 0; n < 4; n++) bfr[n] = *(const short8*)(&Bb[wn + n * 16 + lr][lk]);
    #pragma unroll
    for (int m = 0; m < 4; m++)
      #pragma unroll
      for (int n = 0; n < 4; n++)
        acc[m][n] = __builtin_amdgcn_mfma_f32_16x16x32_bf16(af[m], bfr[n], acc[m][n], 0, 0, 0);
  };

  constexpr int KT = KC / 32;   // >= 32
  // prologue: stage tiles 0 and 1; wait tile 0 landed (tile 1 stays in flight)
  STAGE(As[0], Bs[0], 0);
  STAGE(As[1], Bs[1], 32);
  asm volatile("s_waitcnt vmcnt(4)" ::: "memory");
  __builtin_amdgcn_s_barrier();

  short (*Ar)[32] = As[0]; short (*Br)[32] = Bs[0];   // read (tile t)
  short (*An)[32] = As[1]; short (*Bn)[32] = Bs[1];   // next (tile t+1, in flight/landed)
  short (*Aw)[32] = As[2]; short (*Bw)[32] = Bs[2];   // write (tile t+2)
  #pragma unroll 1
  for (int t = 0; t < KT; ++t) {
    if (t + 2 < KT) {
      STAGE(Aw, Bw, (t + 2) * 32);
      COMPUTE(Ar, Br);
      asm volatile("s_waitcnt vmcnt(4)" ::: "memory");   // tile t+1 landed; t+2 in flight
    } else {
      COMPUTE(Ar, Br);
      asm volatile("s_waitcnt vmcnt(0)" ::: "memory");   // tail: drain remaining
    }
    __builtin_amdgcn_s_barrier();
    short (*ta)[32] = Ar; Ar = An; An = Aw; Aw = ta;
    short (*tb)[32] = Br; Br = Bn; Bn = Bw; Bw = tb;
  }
  // epilogue: frag (row=(lane>>4)*4+r, col=lane&15)
  #pragma unroll
  for (int m = 0; m < 4; m++) {
    #pragma unroll
    for (int n = 0; n < 4; n++) {
      #pragma unroll
      for (int r = 0; r < 4; r++) {
        int row = row0 + wm + m * 16 + (lane >> 4) * 4 + r;
        if (MOE && row >= row_end) continue;
        int col = nbase + wn + n * 16 + lr;
        float v = acc[m][n][r];
        size_t idx = (size_t)row * N + col;
        if (EPI == EPI_BF16) {
          Cb[idx] = f2bf(v);
        } else if (EPI == EPI_RESID) {
          Cf[idx] = v + resid[idx];
        } else if (EPI == EPI_GELU) {
          float g = 0.5f * v * (1.0f + erff(v * 0.70710678118f));
          Cb[idx] = f2bf(g);
        } else {
          Cb[idx] = f2bf(v);
        }
      }
    }
  }
}

// ---------------- Flash attention (T14 async-stage + T5 setprio) ----------------
#define SCL2E 0.18033688011112042f   // 0.125 * log2(e)

__global__ __launch_bounds__(256) void attn_kernel(const short* __restrict__ qkv,
                                                   const short* __restrict__ vT,
                                                   short* __restrict__ o) {
  const int qbase = ((int)gridDim.x - 1 - (int)blockIdx.x) * 64;
  const int bh = blockIdx.y;
  const int b = bh >> 4, h = bh & 15;
  const int w = threadIdx.x >> 6, lane = threadIdx.x & 63;
  const int lr = lane & 15, lkg = lane >> 4, lk = lkg * 8;
  const size_t rs = 3 * Dv;

  __shared__ short Ks[64][72];
  __shared__ short Vs[64][72];
  __shared__ short Ps[4][16][72];

  short8 qf[2];
  {
    size_t qrow = (size_t)(b * Tv + qbase + w * 16 + lr) * rs + h * 64;
    qf[0] = *(const short8*)(qkv + qrow + lk);
    qf[1] = *(const short8*)(qkv + qrow + 32 + lk);
  }
  f32x4 oacc[4];
  #pragma unroll
  for (int n = 0; n < 4; n++) oacc[n] = (f32x4)0.0f;
  float mrow[4] = {-INFINITY, -INFINITY, -INFINITY, -INFINITY};
  float lrow4[4] = {0.f, 0.f, 0.f, 0.f};

  const short* kbase = qkv + (size_t)b * Tv * rs + Dv + h * 64;
  const short* vbase = vT + (size_t)bh * 64 * Tv;

  short8 kreg[2], vreg[2];
  auto LOADKV = [&](int kv0) {
    #pragma unroll
    for (int i = 0; i < 2; i++) {
      int e = threadIdx.x + i * 256;
      int r = e >> 3, c = (e & 7) * 8;
      kreg[i] = *(const short8*)(kbase + (size_t)(kv0 + r) * rs + c);
      vreg[i] = *(const short8*)(vbase + (size_t)r * Tv + kv0 + c);
    }
  };
  auto WRITEKV = [&]() {
    #pragma unroll
    for (int i = 0; i < 2; i++) {
      int e = threadIdx.x + i * 256;
      int r = e >> 3, c = (e & 7) * 8;
      *(short8*)(&Ks[r][c]) = kreg[i];
      *(short8*)(&Vs[r][c]) = vreg[i];
    }
  };

  const int kvend = qbase + 64;
  LOADKV(0);
  WRITEKV();
  __syncthreads();
  for (int kv0 = 0; kv0 < kvend; kv0 += 64) {
    const bool more = (kv0 + 64) < kvend;
    if (more) LOADKV(kv0 + 64);   // global latency hides under QK^T+softmax+PV
    f32x4 s[4];
    __builtin_amdgcn_s_setprio(1);
    #pragma unroll
    for (int n = 0; n < 4; n++) {
      s[n] = (f32x4)0.0f;
      short8 kf0 = *(const short8*)(&Ks[n * 16 + lr][lk]);
      short8 kf1 = *(const short8*)(&Ks[n * 16 + lr][32 + lk]);
      s[n] = __builtin_amdgcn_mfma_f32_16x16x32_bf16(qf[0], kf0, s[n], 0, 0, 0);
      s[n] = __builtin_amdgcn_mfma_f32_16x16x32_bf16(qf[1], kf1, s[n], 0, 0, 0);
    }
    __builtin_amdgcn_s_setprio(0);
    if (kv0 < qbase) {
      #pragma unroll
      for (int n = 0; n < 4; n++)
        #pragma unroll
        for (int r = 0; r < 4; r++) s[n][r] *= SCL2E;
    } else {
      #pragma unroll
      for (int n = 0; n < 4; n++)
        #pragma unroll
        for (int r = 0; r < 4; r++) {
          int tq = qbase + w * 16 + lkg * 4 + r;
          int tk = kv0 + n * 16 + lr;
          s[n][r] = (tk > tq) ? -1e30f : s[n][r] * SCL2E;
        }
    }
    float scr[4];
    #pragma unroll
    for (int r = 0; r < 4; r++) {
      float m = fmaxf(fmaxf(s[0][r], s[1][r]), fmaxf(s[2][r], s[3][r]));
      #pragma unroll
      for (int off = 8; off; off >>= 1) m = fmaxf(m, __shfl_xor(m, off, 64));
      float mnew = fmaxf(mrow[r], m);
      float sc = exp2f(mrow[r] - mnew);
      float rsum = 0.f;
      #pragma unroll
      for (int n = 0; n < 4; n++) { float p = exp2f(s[n][r] - mnew); s[n][r] = p; rsum += p; }
      #pragma unroll
      for (int off = 8; off; off >>= 1) rsum += __shfl_xor(rsum, off, 64);
      lrow4[r] = lrow4[r] * sc + rsum;
      mrow[r] = mnew;
      scr[r] = sc;
    }
    #pragma unroll
    for (int n = 0; n < 4; n++)
      #pragma unroll
      for (int r = 0; r < 4; r++) Ps[w][lkg * 4 + r][n * 16 + lr] = f2bf(s[n][r]);
    #pragma unroll
    for (int n = 0; n < 4; n++)
      #pragma unroll
      for (int r = 0; r < 4; r++) oacc[n][r] *= scr[r];
    __syncthreads();
    __builtin_amdgcn_s_setprio(1);
    #pragma unroll
    for (int n2 = 0; n2 < 4; n2++) {
      short8 pf0 = *(const short8*)(&Ps[w][lr][lk]);
      short8 pf1 = *(const short8*)(&Ps[w][lr][32 + lk]);
      short8 vf0 = *(const short8*)(&Vs[n2 * 16 + lr][lk]);
      short8 vf1 = *(const short8*)(&Vs[n2 * 16 + lr][32 + lk]);
      oacc[n2] = __builtin_amdgcn_mfma_f32_16x16x32_bf16(pf0, vf0, oacc[n2], 0, 0, 0);
      oacc[n2] = __builtin_amdgcn_mfma_f32_16x16x32_bf16(pf1, vf1, oacc[n2], 0, 0, 0);
    }
    __builtin_amdgcn_s_setprio(0);
    __syncthreads();
    if (more) {
      WRITEKV();
      __syncthreads();
    }
  }
  float rinv[4];
  #pragma unroll
  for (int r = 0; r < 4; r++) rinv[r] = 1.0f / lrow4[r];
  #pragma unroll
  for (int n2 = 0; n2 < 4; n2++)
    #pragma unroll
    for (int r = 0; r < 4; r++) {
      int tq = qbase + w * 16 + lkg * 4 + r;
      float v = oacc[n2][r] * rinv[r];
      o[(size_t)(b * Tv + tq) * Dv + h * 64 + n2 * 16 + lr] = f2bf(v);
    }
}

// ---------------- Router ----------------
__global__ __launch_bounds__(256) void router_kernel(const float* __restrict__ x2f,
                                                     const float* __restrict__ rw,
                                                     int* __restrict__ topi,
                                                     float* __restrict__ topp) {
  int w = threadIdx.x >> 6, lane = threadIdx.x & 63;
  int t = blockIdx.x * 4 + w;
  const float* row = x2f + (size_t)t * Dv;
  float acc[8];
  #pragma unroll
  for (int e = 0; e < 8; e++) acc[e] = 0.f;
  for (int i = 0; i < 16; i++) {
    int d = lane + i * 64;
    float xv = row[d];
    const float* rwp = rw + (size_t)d * 8;
    #pragma unroll
    for (int e = 0; e < 8; e++) acc[e] += xv * rwp[e];
  }
  #pragma unroll
  for (int e = 0; e < 8; e++) acc[e] = wredsum(acc[e]);
  if (lane == 0) {
    float mx = acc[0];
    #pragma unroll
    for (int e = 1; e < 8; e++) mx = fmaxf(mx, acc[e]);
    float p[8]; float se = 0.f;
    #pragma unroll
    for (int e = 0; e < 8; e++) { p[e] = expf(acc[e] - mx); se += p[e]; }
    #pragma unroll
    for (int e = 0; e < 8; e++) p[e] /= se;
    int i1 = 0; float p1 = p[0];
    #pragma unroll
    for (int e = 1; e < 8; e++) if (p[e] > p1) { p1 = p[e]; i1 = e; }
    float pm = p[i1]; p[i1] = -1.f;
    int i2 = 0; float p2 = p[0];
    #pragma unroll
    for (int e = 1; e < 8; e++) if (p[e] > p2) { p2 = p[e]; i2 = e; }
    float sum = pm + p2;
    topi[t * 2] = i1; topi[t * 2 + 1] = i2;
    topp[t * 2] = pm / sum; topp[t * 2 + 1] = p2 / sum;
  }
}

// ---------------- bucket build (128-row tiles) ----------------
__global__ void bucket_count(const int* __restrict__ topi, int* __restrict__ offsets,
                             int* __restrict__ cursor) {
  __shared__ int cnt[8];
  if (threadIdx.x < 8) { cnt[threadIdx.x] = 0; cursor[threadIdx.x] = 0; }
  __syncthreads();
  for (int i = threadIdx.x; i < NT * 2; i += 256) atomicAdd(&cnt[topi[i]], 1);
  __syncthreads();
  if (threadIdx.x == 0) {
    int s = 0;
    for (int e = 0; e < 8; e++) { offsets[e] = s; s += cnt[e]; }
    offsets[8] = s;
  }
}
__global__ void bucket_scatter(const int* __restrict__ topi, const int* __restrict__ offsets,
                               int* __restrict__ cursor, int* __restrict__ perm,
                               int* __restrict__ row_of) {
  int i = blockIdx.x * 256 + threadIdx.x;
  if (i >= NT * 2) return;
  int e = topi[i];
  int slot = atomicAdd(&cursor[e], 1);
  int r = offsets[e] + slot;
  perm[r] = i >> 1;
  row_of[i] = r;
}
__global__ void tile_build(const int* __restrict__ offsets, int* __restrict__ tiles) {
  if (threadIdx.x == 0 && blockIdx.x == 0) {
    int nt = 0;
    for (int e = 0; e < 8; e++) {
      int r0 = offsets[e], r1 = offsets[e + 1];
      for (int m = r0; m < r1; m += 128) {
        tiles[1 + nt * 3] = e; tiles[2 + nt * 3] = m; tiles[3 + nt * 3] = r1; nt++;
      }
    }
    tiles[0] = nt;
  }
}

// ---------------- final ----------------
__global__ __launch_bounds__(256) void final_kernel(float* __restrict__ out,
                                                    const short* __restrict__ eout,
                                                    const int* __restrict__ row_of,
                                                    const float* __restrict__ topp) {
  int t = blockIdx.x; int tid = threadIdx.x;
  int r0 = row_of[t * 2], r1 = row_of[t * 2 + 1];
  float p0 = topp[t * 2], p1 = topp[t * 2 + 1];
  #pragma unroll
  for (int i = 0; i < 4; i++) {
    int d = tid + i * 256;
    out[(size_t)t * Dv + d] += p0 * bf2f(eout[(size_t)r0 * Dv + d])
                             + p1 * bf2f(eout[(size_t)r1 * Dv + d]);
  }
}

extern "C" void kernel_launch(void* const* d_in, const int* in_sizes, int n_in,
                              void* d_out, int out_size, void* d_ws, size_t ws_size,
                              hipStream_t stream) {
  const float* x        = (const float*)d_in[0];
  const float* ln1_w    = (const float*)d_in[1];
  const float* wqkv     = (const float*)d_in[2];
  const float* wproj    = (const float*)d_in[3];
  const float* ln2_w    = (const float*)d_in[4];
  const float* router_w = (const float*)d_in[5];
  const float* w1       = (const float*)d_in[6];
  const float* w2       = (const float*)d_in[7];
  float* out = (float*)d_out;
  char* ws = (char*)d_ws;

  size_t off = 0;
  short* wqkvT  = (short*)(ws + off); off += (size_t)3 * Dv * Dv * 2;
  short* wprojT = (short*)(ws + off); off += (size_t)Dv * Dv * 2;
  short* w1T    = (short*)(ws + off); off += (size_t)Ev * Dv * Fv * 2;
  short* w2T    = (short*)(ws + off); off += (size_t)Ev * Fv * Dv * 2;
  char* reg1 = ws + off; off += (size_t)NT * Dv * 2;
  short* hln1 = (short*)reg1;
  short* ob   = (short*)reg1;
  short* x2b  = (short*)reg1;
  char* reg2 = ws + off; off += (size_t)NT * 3 * Dv * 2;
  short* qkvb = (short*)reg2;
  float* xres = (float*)reg2;
  char* reg3 = ws + off; off += (size_t)NT * 2 * Fv * 2;
  short* vT = (short*)reg3;
  short* Hb = (short*)reg3;
  short* eout = (short*)(ws + off); off += (size_t)NT * 2 * Dv * 2;
  int*   topi = (int*)(ws + off);   off += NT * 2 * 4;
  float* topp = (float*)(ws + off); off += NT * 2 * 4;
  int*   offs = (int*)(ws + off);   off += 64;
  int*   cur  = (int*)(ws + off);   off += 64;
  int*   perm = (int*)(ws + off);   off += NT * 2 * 4;
  int*   rowof= (int*)(ws + off);   off += NT * 2 * 4;
  int*   tiles= (int*)(ws + off);   off += 1024;

  // 0. pre-transpose + convert weights to bf16 [N][K]
  transpose_cvt<<<dim3(Dv / 64, 3 * Dv / 64, 1), 256, 0, stream>>>(wqkv, wqkvT, Dv, 3 * Dv);
  transpose_cvt<<<dim3(Dv / 64, Dv / 64, 1), 256, 0, stream>>>(wproj, wprojT, Dv, Dv);
  transpose_cvt<<<dim3(Dv / 64, Fv / 64, Ev), 256, 0, stream>>>(w1, w1T, Dv, Fv);
  transpose_cvt<<<dim3(Fv / 64, Dv / 64, Ev), 256, 0, stream>>>(w2, w2T, Fv, Dv);

  // 1. LN1 -> bf16
  ln_kernel<<<NT, 256, 0, stream>>>(x, ln1_w, nullptr, hln1);
  // 2. QKV  (32x24 = 768 blocks, %8==0)
  gemm_lds<EPI_BF16, false, false, Dv><<<dim3(NT / 128, 3 * Dv / 128), 256, 0, stream>>>(
      hln1, wqkvT, qkvb, nullptr, nullptr, nullptr, nullptr, NT, 3 * Dv);
  // 2.5 V pre-transpose
  vtrans_kernel<<<dim3(Tv / 64, Bv * Hv), 256, 0, stream>>>(qkvb, vT);
  // 3. attention
  attn_kernel<<<dim3(Tv / 64, Bv * Hv), 256, 0, stream>>>(qkvb, vT, ob);
  // 4. xres = x + o @ wproj  (32x8 = 256 blocks)
  gemm_lds<EPI_RESID, false, false, Dv><<<dim3(NT / 128, Dv / 128), 256, 0, stream>>>(
      ob, wprojT, nullptr, xres, x, nullptr, nullptr, NT, Dv);
  // 5. LN2 -> d_out (f32) + bf16 copy
  ln_kernel<<<NT, 256, 0, stream>>>(xres, ln2_w, out, x2b);
  // 6. router
  router_kernel<<<NT / 4, 256, 0, stream>>>(out, router_w, topi, topp);
  // 7. buckets (128-row tiles)
  bucket_count<<<1, 256, 0, stream>>>(topi, offs, cur);
  bucket_scatter<<<NT * 2 / 256, 256, 0, stream>>>(topi, offs, cur, perm, rowof);
  tile_build<<<1, 1, 0, stream>>>(offs, tiles);
  // 8. H = gelu(gather(x2b) @ w1[e])   (72x32 = 2304 blocks, %8==0)
  gemm_lds<EPI_GELU, true, true, Dv><<<dim3(MAXTILES, Fv / 128), 256, 0, stream>>>(
      x2b, w1T, Hb, nullptr, nullptr, perm, tiles, 0, Fv);
  // 9. eout = H @ w2[e]   (72x8 = 576 blocks, %8==0)
  gemm_lds<EPI_BF16, true, false, Fv><<<dim3(MAXTILES, Dv / 128), 256, 0, stream>>>(
      Hb, w2T, eout, nullptr, nullptr, nullptr, tiles, 0, Dv);
  // 10. out += p0*eout[r0] + p1*eout[r1]
  final_kernel<<<NT, 256, 0, stream>>>(out, eout, rowof, topp);
}

// Round 15
// 642.675 us; speedup vs baseline: 1.3306x; 1.3306x over previous
//
#include <hip/hip_runtime.h>
#include <hip/hip_bf16.h>
#include <math.h>

// ---- problem constants ----
#define Bv 2
#define Tv 2048
#define Dv 1024
#define Hv 16
#define Ev 8
#define Kv 2
#define Fv 4096
#define HDv 64
#define NT 4096   // B*T tokens
#define MAXTILES 72

typedef __attribute__((ext_vector_type(8))) short short8;
typedef __attribute__((ext_vector_type(4))) float f32x4;

__device__ __forceinline__ short f2bf(float f) {
  unsigned u = __builtin_bit_cast(unsigned, f);
  u += 0x7fffu + ((u >> 16) & 1u);
  return (short)(u >> 16);
}
__device__ __forceinline__ float bf2f(short s) {
  unsigned u = ((unsigned)(unsigned short)s) << 16;
  return __builtin_bit_cast(float, u);
}
__device__ __forceinline__ float wredsum(float s) {
  #pragma unroll
  for (int off = 32; off; off >>= 1) s += __shfl_down(s, off, 64);
  return s;
}
// async global->LDS, 16B per lane; LDS dest = wave-uniform base + lane*16
__device__ __forceinline__ void gl_lds16(const short* g, short* l) {
  __builtin_amdgcn_global_load_lds(
      (const __attribute__((address_space(1))) unsigned int*)g,
      (__attribute__((address_space(3))) unsigned int*)l, 16, 0, 0);
}

// ---------------- transpose + fp32->bf16 convert ----------------
__global__ __launch_bounds__(256) void transpose_cvt(const float* __restrict__ in,
                                                     short* __restrict__ out,
                                                     int Kd, int Nd) {
  __shared__ float tile[64][65];
  const float* inb = in + (size_t)blockIdx.z * Kd * Nd;
  short* outb = out + (size_t)blockIdx.z * Kd * Nd;
  const int k0 = blockIdx.x * 64, n0 = blockIdx.y * 64;
  const int rr = threadIdx.x >> 4, cc = (threadIdx.x & 15) * 4;
  #pragma unroll
  for (int i = 0; i < 4; i++) {
    int r = rr + i * 16;
    f32x4 v = *(const f32x4*)(inb + (size_t)(k0 + r) * Nd + n0 + cc);
    tile[r][cc] = v[0]; tile[r][cc + 1] = v[1];
    tile[r][cc + 2] = v[2]; tile[r][cc + 3] = v[3];
  }
  __syncthreads();
  #pragma unroll
  for (int i = 0; i < 2; i++) {
    int e = threadIdx.x + i * 256;
    int n = e >> 3, c = (e & 7) * 8;
    short8 v;
    #pragma unroll
    for (int j = 0; j < 8; j++) v[j] = f2bf(tile[c + j][n]);
    *(short8*)(outb + (size_t)(n0 + n) * Kd + k0 + c) = v;
  }
}

// ---------------- V pre-transpose ----------------
__global__ __launch_bounds__(256) void vtrans_kernel(const short* __restrict__ qkv,
                                                     short* __restrict__ vT) {
  __shared__ short tile[64][72];
  const int t0 = blockIdx.x * 64;
  const int bh = blockIdx.y;
  const int b = bh >> 4, h = bh & 15;
  #pragma unroll
  for (int i = 0; i < 2; i++) {
    int e = threadIdx.x + i * 256;
    int r = e >> 3, c = (e & 7) * 8;
    short8 v = *(const short8*)(qkv + (size_t)(b * Tv + t0 + r) * 3072 + 2048 + h * 64 + c);
    *(short8*)(&tile[r][c]) = v;
  }
  __syncthreads();
  #pragma unroll
  for (int i = 0; i < 2; i++) {
    int e = threadIdx.x + i * 256;
    int d = e >> 3, c = (e & 7) * 8;
    short8 v;
    #pragma unroll
    for (int j = 0; j < 8; j++) v[j] = tile[c + j][d];
    *(short8*)(vT + ((size_t)bh * 64 + d) * Tv + t0 + c) = v;
  }
}

// ---------------- LayerNorm ----------------
__global__ __launch_bounds__(256) void ln_kernel(const float* __restrict__ in,
                                                 const float* __restrict__ w,
                                                 float* __restrict__ outf,
                                                 short* __restrict__ outb) {
  int t = blockIdx.x;
  int tid = threadIdx.x;
  const float* row = in + (size_t)t * Dv;
  float v[4]; float s = 0.f;
  #pragma unroll
  for (int i = 0; i < 4; i++) { v[i] = row[tid + i * 256]; s += v[i]; }
  s = wredsum(s);
  __shared__ float red[4], red2[4];
  int wv = tid >> 6, ln = tid & 63;
  if (ln == 0) red[wv] = s;
  __syncthreads();
  float mu = (red[0] + red[1] + red[2] + red[3]) * (1.f / Dv);
  float vs = 0.f;
  #pragma unroll
  for (int i = 0; i < 4; i++) { float d = v[i] - mu; vs += d * d; }
  vs = wredsum(vs);
  if (ln == 0) red2[wv] = vs;
  __syncthreads();
  float var = (red2[0] + red2[1] + red2[2] + red2[3]) * (1.f / Dv);
  float inv = rsqrtf(var + 1e-5f);
  #pragma unroll
  for (int i = 0; i < 4; i++) {
    int d = tid + i * 256;
    float o = (v[i] - mu) * inv * w[d];
    if (outf) outf[(size_t)t * Dv + d] = o;
    if (outb) outb[(size_t)t * Dv + d] = f2bf(o);
  }
}

enum { EPI_BF16 = 0, EPI_RESID = 1, EPI_GELU = 2 };

// ---------------- m97-structure GEMM: 128x128 tile, BK=32, 4 waves (round-11 best) ----------------
// A[M][KC] bf16 x Bt[N][KC] bf16. global_load_lds width=16, linear LDS, single buf.
// K is a TEMPLATE constant: outer loop steps 128 elems (unroll 1), inner 4 K-steps
// unrolled with compile-time offsets so staging addresses fold into the
// instruction's offset immediate. T1 XCD-chunk swizzle (nwg % 8 == 0).
template<int EPI, bool MOE, bool INDIRECT, int KC>
__global__ __launch_bounds__(256) void gemm_lds(
    const short* __restrict__ A, const short* __restrict__ Bt,
    short* __restrict__ Cb, float* __restrict__ Cf,
    const float* __restrict__ resid,
    const int* __restrict__ perm, const int* __restrict__ tiles,
    int M, int N) {
  __shared__ short As[128][32];   // linear: required by global_load_lds
  __shared__ short Bs[128][32];
  const int nwg = gridDim.x * gridDim.y;
  const int orig = blockIdx.y * gridDim.x + blockIdx.x;
  const int cpx = nwg >> 3;
  const int wgid = (orig & 7) * cpx + (orig >> 3);
  const int mt = wgid % gridDim.x;
  const int npan = wgid / gridDim.x;

  int row0, row_end;
  const short* Bp = Bt;
  if (MOE) {
    int ntile = tiles[0];
    if (mt >= ntile) return;
    int e   = tiles[1 + mt * 3];
    row0    = tiles[2 + mt * 3];
    row_end = tiles[3 + mt * 3];
    Bp = Bt + (size_t)e * KC * N;
  } else {
    row0 = mt * 128; row_end = M;
  }
  const int nbase = npan * 128;
  const int tid = threadIdx.x;
  const int lane = tid & 63;
  const int w = tid >> 6;
  const int wm = (w >> 1) * 64, wn = (w & 1) * 64;
  const int lr = lane & 15, lk = (lane >> 4) * 8;

  // staging: one wave-load = 64 lanes x 16B = 16 rows of 64B (32 bf16)
  const int lrow = lane >> 2, lcol = (lane & 3) * 8;
  const short* asrc[2]; short* adst[2];
  const short* bsrc[2]; short* bdst[2];
  #pragma unroll
  for (int i = 0; i < 2; i++) {
    int grow = row0 + w * 16 + i * 64 + lrow;
    if (MOE) grow = min(grow, row_end - 1);
    int arow = INDIRECT ? perm[grow] : grow;
    asrc[i] = A + (size_t)arow * KC + lcol;
    adst[i] = &As[w * 16 + i * 64][0];
    bsrc[i] = Bp + (size_t)(nbase + w * 16 + i * 64 + lrow) * KC + lcol;
    bdst[i] = &Bs[w * 16 + i * 64][0];
  }

  f32x4 acc[4][4];
  #pragma unroll
  for (int m = 0; m < 4; m++)
    #pragma unroll
    for (int n = 0; n < 4; n++) acc[m][n] = (f32x4)0.0f;

  #pragma unroll 1
  for (int k0 = 0; k0 < KC; k0 += 128) {
    #pragma unroll
    for (int j = 0; j < 4; j++) {           // compile-time j -> offset immediates
      #pragma unroll
      for (int i = 0; i < 2; i++) {
        gl_lds16(asrc[i] + k0 + j * 32, adst[i]);
        gl_lds16(bsrc[i] + k0 + j * 32, bdst[i]);
      }
      __syncthreads();
      short8 af[4], bfr[4];
      #pragma unroll
      for (int m = 0; m < 4; m++) af[m] = *(const short8*)(&As[wm + m * 16 + lr][lk]);
      #pragma unroll
      for (int n = 0; n < 4; n++) bfr[n] = *(const short8*)(&Bs[wn + n * 16 + lr][lk]);
      #pragma unroll
      for (int m = 0; m < 4; m++)
        #pragma unroll
        for (int n = 0; n < 4; n++)
          acc[m][n] = __builtin_amdgcn_mfma_f32_16x16x32_bf16(af[m], bfr[n], acc[m][n], 0, 0, 0);
      __syncthreads();
    }
  }
  // epilogue: frag (row=(lane>>4)*4+r, col=lane&15)
  #pragma unroll
  for (int m = 0; m < 4; m++) {
    #pragma unroll
    for (int n = 0; n < 4; n++) {
      #pragma unroll
      for (int r = 0; r < 4; r++) {
        int row = row0 + wm + m * 16 + (lane >> 4) * 4 + r;
        if (MOE && row >= row_end) continue;
        int col = nbase + wn + n * 16 + lr;
        float v = acc[m][n][r];
        size_t idx = (size_t)row * N + col;
        if (EPI == EPI_BF16) {
          Cb[idx] = f2bf(v);
        } else if (EPI == EPI_RESID) {
          Cf[idx] = v + resid[idx];
        } else if (EPI == EPI_GELU) {
          float g = 0.5f * v * (1.0f + erff(v * 0.70710678118f));
          Cb[idx] = f2bf(g);
        } else {
          Cb[idx] = f2bf(v);
        }
      }
    }
  }
}

// ---------------- Flash attention (T14 async-stage + T5 setprio) ----------------
#define SCL2E 0.18033688011112042f   // 0.125 * log2(e)

__global__ __launch_bounds__(256) void attn_kernel(const short* __restrict__ qkv,
                                                   const short* __restrict__ vT,
                                                   short* __restrict__ o) {
  const int qbase = ((int)gridDim.x - 1 - (int)blockIdx.x) * 64;
  const int bh = blockIdx.y;
  const int b = bh >> 4, h = bh & 15;
  const int w = threadIdx.x >> 6, lane = threadIdx.x & 63;
  const int lr = lane & 15, lkg = lane >> 4, lk = lkg * 8;
  const size_t rs = 3 * Dv;

  __shared__ short Ks[64][72];
  __shared__ short Vs[64][72];
  __shared__ short Ps[4][16][72];

  short8 qf[2];
  {
    size_t qrow = (size_t)(b * Tv + qbase + w * 16 + lr) * rs + h * 64;
    qf[0] = *(const short8*)(qkv + qrow + lk);
    qf[1] = *(const short8*)(qkv + qrow + 32 + lk);
  }
  f32x4 oacc[4];
  #pragma unroll
  for (int n = 0; n < 4; n++) oacc[n] = (f32x4)0.0f;
  float mrow[4] = {-INFINITY, -INFINITY, -INFINITY, -INFINITY};
  float lrow4[4] = {0.f, 0.f, 0.f, 0.f};

  const short* kbase = qkv + (size_t)b * Tv * rs + Dv + h * 64;
  const short* vbase = vT + (size_t)bh * 64 * Tv;

  short8 kreg[2], vreg[2];
  auto LOADKV = [&](int kv0) {
    #pragma unroll
    for (int i = 0; i < 2; i++) {
      int e = threadIdx.x + i * 256;
      int r = e >> 3, c = (e & 7) * 8;
      kreg[i] = *(const short8*)(kbase + (size_t)(kv0 + r) * rs + c);
      vreg[i] = *(const short8*)(vbase + (size_t)r * Tv + kv0 + c);
    }
  };
  auto WRITEKV = [&]() {
    #pragma unroll
    for (int i = 0; i < 2; i++) {
      int e = threadIdx.x + i * 256;
      int r = e >> 3, c = (e & 7) * 8;
      *(short8*)(&Ks[r][c]) = kreg[i];
      *(short8*)(&Vs[r][c]) = vreg[i];
    }
  };

  const int kvend = qbase + 64;
  LOADKV(0);
  WRITEKV();
  __syncthreads();
  for (int kv0 = 0; kv0 < kvend; kv0 += 64) {
    const bool more = (kv0 + 64) < kvend;
    if (more) LOADKV(kv0 + 64);   // global latency hides under QK^T+softmax+PV
    f32x4 s[4];
    __builtin_amdgcn_s_setprio(1);
    #pragma unroll
    for (int n = 0; n < 4; n++) {
      s[n] = (f32x4)0.0f;
      short8 kf0 = *(const short8*)(&Ks[n * 16 + lr][lk]);
      short8 kf1 = *(const short8*)(&Ks[n * 16 + lr][32 + lk]);
      s[n] = __builtin_amdgcn_mfma_f32_16x16x32_bf16(qf[0], kf0, s[n], 0, 0, 0);
      s[n] = __builtin_amdgcn_mfma_f32_16x16x32_bf16(qf[1], kf1, s[n], 0, 0, 0);
    }
    __builtin_amdgcn_s_setprio(0);
    if (kv0 < qbase) {
      #pragma unroll
      for (int n = 0; n < 4; n++)
        #pragma unroll
        for (int r = 0; r < 4; r++) s[n][r] *= SCL2E;
    } else {
      #pragma unroll
      for (int n = 0; n < 4; n++)
        #pragma unroll
        for (int r = 0; r < 4; r++) {
          int tq = qbase + w * 16 + lkg * 4 + r;
          int tk = kv0 + n * 16 + lr;
          s[n][r] = (tk > tq) ? -1e30f : s[n][r] * SCL2E;
        }
    }
    float scr[4];
    #pragma unroll
    for (int r = 0; r < 4; r++) {
      float m = fmaxf(fmaxf(s[0][r], s[1][r]), fmaxf(s[2][r], s[3][r]));
      #pragma unroll
      for (int off = 8; off; off >>= 1) m = fmaxf(m, __shfl_xor(m, off, 64));
      float mnew = fmaxf(mrow[r], m);
      float sc = exp2f(mrow[r] - mnew);
      float rsum = 0.f;
      #pragma unroll
      for (int n = 0; n < 4; n++) { float p = exp2f(s[n][r] - mnew); s[n][r] = p; rsum += p; }
      #pragma unroll
      for (int off = 8; off; off >>= 1) rsum += __shfl_xor(rsum, off, 64);
      lrow4[r] = lrow4[r] * sc + rsum;
      mrow[r] = mnew;
      scr[r] = sc;
    }
    #pragma unroll
    for (int n = 0; n < 4; n++)
      #pragma unroll
      for (int r = 0; r < 4; r++) Ps[w][lkg * 4 + r][n * 16 + lr] = f2bf(s[n][r]);
    #pragma unroll
    for (int n = 0; n < 4; n++)
      #pragma unroll
      for (int r = 0; r < 4; r++) oacc[n][r] *= scr[r];
    __syncthreads();
    __builtin_amdgcn_s_setprio(1);
    #pragma unroll
    for (int n2 = 0; n2 < 4; n2++) {
      short8 pf0 = *(const short8*)(&Ps[w][lr][lk]);
      short8 pf1 = *(const short8*)(&Ps[w][lr][32 + lk]);
      short8 vf0 = *(const short8*)(&Vs[n2 * 16 + lr][lk]);
      short8 vf1 = *(const short8*)(&Vs[n2 * 16 + lr][32 + lk]);
      oacc[n2] = __builtin_amdgcn_mfma_f32_16x16x32_bf16(pf0, vf0, oacc[n2], 0, 0, 0);
      oacc[n2] = __builtin_amdgcn_mfma_f32_16x16x32_bf16(pf1, vf1, oacc[n2], 0, 0, 0);
    }
    __builtin_amdgcn_s_setprio(0);
    __syncthreads();
    if (more) {
      WRITEKV();
      __syncthreads();
    }
  }
  float rinv[4];
  #pragma unroll
  for (int r = 0; r < 4; r++) rinv[r] = 1.0f / lrow4[r];
  #pragma unroll
  for (int n2 = 0; n2 < 4; n2++)
    #pragma unroll
    for (int r = 0; r < 4; r++) {
      int tq = qbase + w * 16 + lkg * 4 + r;
      float v = oacc[n2][r] * rinv[r];
      o[(size_t)(b * Tv + tq) * Dv + h * 64 + n2 * 16 + lr] = f2bf(v);
    }
}

// ---------------- Router ----------------
__global__ __launch_bounds__(256) void router_kernel(const float* __restrict__ x2f,
                                                     const float* __restrict__ rw,
                                                     int* __restrict__ topi,
                                                     float* __restrict__ topp) {
  int w = threadIdx.x >> 6, lane = threadIdx.x & 63;
  int t = blockIdx.x * 4 + w;
  const float* row = x2f + (size_t)t * Dv;
  float acc[8];
  #pragma unroll
  for (int e = 0; e < 8; e++) acc[e] = 0.f;
  for (int i = 0; i < 16; i++) {
    int d = lane + i * 64;
    float xv = row[d];
    const float* rwp = rw + (size_t)d * 8;
    #pragma unroll
    for (int e = 0; e < 8; e++) acc[e] += xv * rwp[e];
  }
  #pragma unroll
  for (int e = 0; e < 8; e++) acc[e] = wredsum(acc[e]);
  if (lane == 0) {
    float mx = acc[0];
    #pragma unroll
    for (int e = 1; e < 8; e++) mx = fmaxf(mx, acc[e]);
    float p[8]; float se = 0.f;
    #pragma unroll
    for (int e = 0; e < 8; e++) { p[e] = expf(acc[e] - mx); se += p[e]; }
    #pragma unroll
    for (int e = 0; e < 8; e++) p[e] /= se;
    int i1 = 0; float p1 = p[0];
    #pragma unroll
    for (int e = 1; e < 8; e++) if (p[e] > p1) { p1 = p[e]; i1 = e; }
    float pm = p[i1]; p[i1] = -1.f;
    int i2 = 0; float p2 = p[0];
    #pragma unroll
    for (int e = 1; e < 8; e++) if (p[e] > p2) { p2 = p[e]; i2 = e; }
    float sum = pm + p2;
    topi[t * 2] = i1; topi[t * 2 + 1] = i2;
    topp[t * 2] = pm / sum; topp[t * 2 + 1] = p2 / sum;
  }
}

// ---------------- bucket build (128-row tiles) ----------------
__global__ void bucket_count(const int* __restrict__ topi, int* __restrict__ offsets,
                             int* __restrict__ cursor) {
  __shared__ int cnt[8];
  if (threadIdx.x < 8) { cnt[threadIdx.x] = 0; cursor[threadIdx.x] = 0; }
  __syncthreads();
  for (int i = threadIdx.x; i < NT * 2; i += 256) atomicAdd(&cnt[topi[i]], 1);
  __syncthreads();
  if (threadIdx.x == 0) {
    int s = 0;
    for (int e = 0; e < 8; e++) { offsets[e] = s; s += cnt[e]; }
    offsets[8] = s;
  }
}
__global__ void bucket_scatter(const int* __restrict__ topi, const int* __restrict__ offsets,
                               int* __restrict__ cursor, int* __restrict__ perm,
                               int* __restrict__ row_of) {
  int i = blockIdx.x * 256 + threadIdx.x;
  if (i >= NT * 2) return;
  int e = topi[i];
  int slot = atomicAdd(&cursor[e], 1);
  int r = offsets[e] + slot;
  perm[r] = i >> 1;
  row_of[i] = r;
}
__global__ void tile_build(const int* __restrict__ offsets, int* __restrict__ tiles) {
  if (threadIdx.x == 0 && blockIdx.x == 0) {
    int nt = 0;
    for (int e = 0; e < 8; e++) {
      int r0 = offsets[e], r1 = offsets[e + 1];
      for (int m = r0; m < r1; m += 128) {
        tiles[1 + nt * 3] = e; tiles[2 + nt * 3] = m; tiles[3 + nt * 3] = r1; nt++;
      }
    }
    tiles[0] = nt;
  }
}

// ---------------- final ----------------
__global__ __launch_bounds__(256) void final_kernel(float* __restrict__ out,
                                                    const short* __restrict__ eout,
                                                    const int* __restrict__ row_of,
                                                    const float* __restrict__ topp) {
  int t = blockIdx.x; int tid = threadIdx.x;
  int r0 = row_of[t * 2], r1 = row_of[t * 2 + 1];
  float p0 = topp[t * 2], p1 = topp[t * 2 + 1];
  #pragma unroll
  for (int i = 0; i < 4; i++) {
    int d = tid + i * 256;
    out[(size_t)t * Dv + d] += p0 * bf2f(eout[(size_t)r0 * Dv + d])
                             + p1 * bf2f(eout[(size_t)r1 * Dv + d]);
  }
}

extern "C" void kernel_launch(void* const* d_in, const int* in_sizes, int n_in,
                              void* d_out, int out_size, void* d_ws, size_t ws_size,
                              hipStream_t stream) {
  const float* x        = (const float*)d_in[0];
  const float* ln1_w    = (const float*)d_in[1];
  const float* wqkv     = (const float*)d_in[2];
  const float* wproj    = (const float*)d_in[3];
  const float* ln2_w    = (const float*)d_in[4];
  const float* router_w = (const float*)d_in[5];
  const float* w1       = (const float*)d_in[6];
  const float* w2       = (const float*)d_in[7];
  float* out = (float*)d_out;
  char* ws = (char*)d_ws;

  size_t off = 0;
  short* wqkvT  = (short*)(ws + off); off += (size_t)3 * Dv * Dv * 2;
  short* wprojT = (short*)(ws + off); off += (size_t)Dv * Dv * 2;
  short* w1T    = (short*)(ws + off); off += (size_t)Ev * Dv * Fv * 2;
  short* w2T    = (short*)(ws + off); off += (size_t)Ev * Fv * Dv * 2;
  char* reg1 = ws + off; off += (size_t)NT * Dv * 2;
  short* hln1 = (short*)reg1;
  short* ob   = (short*)reg1;
  short* x2b  = (short*)reg1;
  char* reg2 = ws + off; off += (size_t)NT * 3 * Dv * 2;
  short* qkvb = (short*)reg2;
  float* xres = (float*)reg2;
  char* reg3 = ws + off; off += (size_t)NT * 2 * Fv * 2;
  short* vT = (short*)reg3;
  short* Hb = (short*)reg3;
  short* eout = (short*)(ws + off); off += (size_t)NT * 2 * Dv * 2;
  int*   topi = (int*)(ws + off);   off += NT * 2 * 4;
  float* topp = (float*)(ws + off); off += NT * 2 * 4;
  int*   offs = (int*)(ws + off);   off += 64;
  int*   cur  = (int*)(ws + off);   off += 64;
  int*   perm = (int*)(ws + off);   off += NT * 2 * 4;
  int*   rowof= (int*)(ws + off);   off += NT * 2 * 4;
  int*   tiles= (int*)(ws + off);   off += 1024;

  // 0. pre-transpose + convert weights to bf16 [N][K]
  transpose_cvt<<<dim3(Dv / 64, 3 * Dv / 64, 1), 256, 0, stream>>>(wqkv, wqkvT, Dv, 3 * Dv);
  transpose_cvt<<<dim3(Dv / 64, Dv / 64, 1), 256, 0, stream>>>(wproj, wprojT, Dv, Dv);
  transpose_cvt<<<dim3(Dv / 64, Fv / 64, Ev), 256, 0, stream>>>(w1, w1T, Dv, Fv);
  transpose_cvt<<<dim3(Fv / 64, Dv / 64, Ev), 256, 0, stream>>>(w2, w2T, Fv, Dv);

  // 1. LN1 -> bf16
  ln_kernel<<<NT, 256, 0, stream>>>(x, ln1_w, nullptr, hln1);
  // 2. QKV  (32x24 = 768 blocks, %8==0)
  gemm_lds<EPI_BF16, false, false, Dv><<<dim3(NT / 128, 3 * Dv / 128), 256, 0, stream>>>(
      hln1, wqkvT, qkvb, nullptr, nullptr, nullptr, nullptr, NT, 3 * Dv);
  // 2.5 V pre-transpose
  vtrans_kernel<<<dim3(Tv / 64, Bv * Hv), 256, 0, stream>>>(qkvb, vT);
  // 3. attention
  attn_kernel<<<dim3(Tv / 64, Bv * Hv), 256, 0, stream>>>(qkvb, vT, ob);
  // 4. xres = x + o @ wproj  (32x8 = 256 blocks)
  gemm_lds<EPI_RESID, false, false, Dv><<<dim3(NT / 128, Dv / 128), 256, 0, stream>>>(
      ob, wprojT, nullptr, xres, x, nullptr, nullptr, NT, Dv);
  // 5. LN2 -> d_out (f32) + bf16 copy
  ln_kernel<<<NT, 256, 0, stream>>>(xres, ln2_w, out, x2b);
  // 6. router
  router_kernel<<<NT / 4, 256, 0, stream>>>(out, router_w, topi, topp);
  // 7. buckets (128-row tiles)
  bucket_count<<<1, 256, 0, stream>>>(topi, offs, cur);
  bucket_scatter<<<NT * 2 / 256, 256, 0, stream>>>(topi, offs, cur, perm, rowof);
  tile_build<<<1, 1, 0, stream>>>(offs, tiles);
  // 8. H = gelu(gather(x2b) @ w1[e])   (72x32 = 2304 blocks, %8==0)
  gemm_lds<EPI_GELU, true, true, Dv><<<dim3(MAXTILES, Fv / 128), 256, 0, stream>>>(
      x2b, w1T, Hb, nullptr, nullptr, perm, tiles, 0, Fv);
  // 9. eout = H @ w2[e]   (72x8 = 576 blocks, %8==0)
  gemm_lds<EPI_BF16, true, false, Fv><<<dim3(MAXTILES, Dv / 128), 256, 0, stream>>>(
      Hb, w2T, eout, nullptr, nullptr, nullptr, tiles, 0, Dv);
  // 10. out += p0*eout[r0] + p1*eout[r1]
  final_kernel<<<NT, 256, 0, stream>>>(out, eout, rowof, topp);
}

// Round 16
// 579.852 us; speedup vs baseline: 1.4748x; 1.1083x over previous
//
#include <hip/hip_runtime.h>
#include <hip/hip_bf16.h>
#include <math.h>

// ---- problem constants ----
#define Bv 2
#define Tv 2048
#define Dv 1024
#define Hv 16
#define Ev 8
#define Kv 2
#define Fv 4096
#define HDv 64
#define NT 4096   // B*T tokens
#define MAXTILES 72

typedef __attribute__((ext_vector_type(8))) short short8;
typedef __attribute__((ext_vector_type(4))) float f32x4;

__device__ __forceinline__ short f2bf(float f) {
  unsigned u = __builtin_bit_cast(unsigned, f);
  u += 0x7fffu + ((u >> 16) & 1u);
  return (short)(u >> 16);
}
__device__ __forceinline__ float bf2f(short s) {
  unsigned u = ((unsigned)(unsigned short)s) << 16;
  return __builtin_bit_cast(float, u);
}
__device__ __forceinline__ float wredsum(float s) {
  #pragma unroll
  for (int off = 32; off; off >>= 1) s += __shfl_down(s, off, 64);
  return s;
}
// async global->LDS, 16B per lane; LDS dest = wave-uniform base + lane*16
__device__ __forceinline__ void gl_lds16(const short* g, short* l) {
  __builtin_amdgcn_global_load_lds(
      (const __attribute__((address_space(1))) unsigned int*)g,
      (__attribute__((address_space(3))) unsigned int*)l, 16, 0, 0);
}

// ---------------- transpose + fp32->bf16 convert ----------------
__global__ __launch_bounds__(256) void transpose_cvt(const float* __restrict__ in,
                                                     short* __restrict__ out,
                                                     int Kd, int Nd) {
  __shared__ float tile[64][65];
  const float* inb = in + (size_t)blockIdx.z * Kd * Nd;
  short* outb = out + (size_t)blockIdx.z * Kd * Nd;
  const int k0 = blockIdx.x * 64, n0 = blockIdx.y * 64;
  const int rr = threadIdx.x >> 4, cc = (threadIdx.x & 15) * 4;
  #pragma unroll
  for (int i = 0; i < 4; i++) {
    int r = rr + i * 16;
    f32x4 v = *(const f32x4*)(inb + (size_t)(k0 + r) * Nd + n0 + cc);
    tile[r][cc] = v[0]; tile[r][cc + 1] = v[1];
    tile[r][cc + 2] = v[2]; tile[r][cc + 3] = v[3];
  }
  __syncthreads();
  #pragma unroll
  for (int i = 0; i < 2; i++) {
    int e = threadIdx.x + i * 256;
    int n = e >> 3, c = (e & 7) * 8;
    short8 v;
    #pragma unroll
    for (int j = 0; j < 8; j++) v[j] = f2bf(tile[c + j][n]);
    *(short8*)(outb + (size_t)(n0 + n) * Kd + k0 + c) = v;
  }
}

// ---------------- V pre-transpose ----------------
__global__ __launch_bounds__(256) void vtrans_kernel(const short* __restrict__ qkv,
                                                     short* __restrict__ vT) {
  __shared__ short tile[64][72];
  const int t0 = blockIdx.x * 64;
  const int bh = blockIdx.y;
  const int b = bh >> 4, h = bh & 15;
  #pragma unroll
  for (int i = 0; i < 2; i++) {
    int e = threadIdx.x + i * 256;
    int r = e >> 3, c = (e & 7) * 8;
    short8 v = *(const short8*)(qkv + (size_t)(b * Tv + t0 + r) * 3072 + 2048 + h * 64 + c);
    *(short8*)(&tile[r][c]) = v;
  }
  __syncthreads();
  #pragma unroll
  for (int i = 0; i < 2; i++) {
    int e = threadIdx.x + i * 256;
    int d = e >> 3, c = (e & 7) * 8;
    short8 v;
    #pragma unroll
    for (int j = 0; j < 8; j++) v[j] = tile[c + j][d];
    *(short8*)(vT + ((size_t)bh * 64 + d) * Tv + t0 + c) = v;
  }
}

// ---------------- LayerNorm ----------------
__global__ __launch_bounds__(256) void ln_kernel(const float* __restrict__ in,
                                                 const float* __restrict__ w,
                                                 float* __restrict__ outf,
                                                 short* __restrict__ outb) {
  int t = blockIdx.x;
  int tid = threadIdx.x;
  const float* row = in + (size_t)t * Dv;
  float v[4]; float s = 0.f;
  #pragma unroll
  for (int i = 0; i < 4; i++) { v[i] = row[tid + i * 256]; s += v[i]; }
  s = wredsum(s);
  __shared__ float red[4], red2[4];
  int wv = tid >> 6, ln = tid & 63;
  if (ln == 0) red[wv] = s;
  __syncthreads();
  float mu = (red[0] + red[1] + red[2] + red[3]) * (1.f / Dv);
  float vs = 0.f;
  #pragma unroll
  for (int i = 0; i < 4; i++) { float d = v[i] - mu; vs += d * d; }
  vs = wredsum(vs);
  if (ln == 0) red2[wv] = vs;
  __syncthreads();
  float var = (red2[0] + red2[1] + red2[2] + red2[3]) * (1.f / Dv);
  float inv = rsqrtf(var + 1e-5f);
  #pragma unroll
  for (int i = 0; i < 4; i++) {
    int d = tid + i * 256;
    float o = (v[i] - mu) * inv * w[d];
    if (outf) outf[(size_t)t * Dv + d] = o;
    if (outb) outb[(size_t)t * Dv + d] = f2bf(o);
  }
}

enum { EPI_BF16 = 0, EPI_RESID = 1, EPI_GELU = 2 };

// ---------------- m97-structure GEMM: 128x128 tile, BK=32, 4 waves (round-11 best) ----------------
template<int EPI, bool MOE, bool INDIRECT, int KC>
__global__ __launch_bounds__(256) void gemm_lds(
    const short* __restrict__ A, const short* __restrict__ Bt,
    short* __restrict__ Cb, float* __restrict__ Cf,
    const float* __restrict__ resid,
    const int* __restrict__ perm, const int* __restrict__ tiles,
    int M, int N) {
  __shared__ short As[128][32];   // linear: required by global_load_lds
  __shared__ short Bs[128][32];
  const int nwg = gridDim.x * gridDim.y;
  const int orig = blockIdx.y * gridDim.x + blockIdx.x;
  const int cpx = nwg >> 3;
  const int wgid = (orig & 7) * cpx + (orig >> 3);
  const int mt = wgid % gridDim.x;
  const int npan = wgid / gridDim.x;

  int row0, row_end;
  const short* Bp = Bt;
  if (MOE) {
    int ntile = tiles[0];
    if (mt >= ntile) return;
    int e   = tiles[1 + mt * 3];
    row0    = tiles[2 + mt * 3];
    row_end = tiles[3 + mt * 3];
    Bp = Bt + (size_t)e * KC * N;
  } else {
    row0 = mt * 128; row_end = M;
  }
  const int nbase = npan * 128;
  const int tid = threadIdx.x;
  const int lane = tid & 63;
  const int w = tid >> 6;
  const int wm = (w >> 1) * 64, wn = (w & 1) * 64;
  const int lr = lane & 15, lk = (lane >> 4) * 8;

  const int lrow = lane >> 2, lcol = (lane & 3) * 8;
  const short* asrc[2]; short* adst[2];
  const short* bsrc[2]; short* bdst[2];
  #pragma unroll
  for (int i = 0; i < 2; i++) {
    int grow = row0 + w * 16 + i * 64 + lrow;
    if (MOE) grow = min(grow, row_end - 1);
    int arow = INDIRECT ? perm[grow] : grow;
    asrc[i] = A + (size_t)arow * KC + lcol;
    adst[i] = &As[w * 16 + i * 64][0];
    bsrc[i] = Bp + (size_t)(nbase + w * 16 + i * 64 + lrow) * KC + lcol;
    bdst[i] = &Bs[w * 16 + i * 64][0];
  }

  f32x4 acc[4][4];
  #pragma unroll
  for (int m = 0; m < 4; m++)
    #pragma unroll
    for (int n = 0; n < 4; n++) acc[m][n] = (f32x4)0.0f;

  #pragma unroll 1
  for (int k0 = 0; k0 < KC; k0 += 128) {
    #pragma unroll
    for (int j = 0; j < 4; j++) {           // compile-time j -> offset immediates
      #pragma unroll
      for (int i = 0; i < 2; i++) {
        gl_lds16(asrc[i] + k0 + j * 32, adst[i]);
        gl_lds16(bsrc[i] + k0 + j * 32, bdst[i]);
      }
      __syncthreads();
      short8 af[4], bfr[4];
      #pragma unroll
      for (int m = 0; m < 4; m++) af[m] = *(const short8*)(&As[wm + m * 16 + lr][lk]);
      #pragma unroll
      for (int n = 0; n < 4; n++) bfr[n] = *(const short8*)(&Bs[wn + n * 16 + lr][lk]);
      #pragma unroll
      for (int m = 0; m < 4; m++)
        #pragma unroll
        for (int n = 0; n < 4; n++)
          acc[m][n] = __builtin_amdgcn_mfma_f32_16x16x32_bf16(af[m], bfr[n], acc[m][n], 0, 0, 0);
      __syncthreads();
    }
  }
  #pragma unroll
  for (int m = 0; m < 4; m++) {
    #pragma unroll
    for (int n = 0; n < 4; n++) {
      #pragma unroll
      for (int r = 0; r < 4; r++) {
        int row = row0 + wm + m * 16 + (lane >> 4) * 4 + r;
        if (MOE && row >= row_end) continue;
        int col = nbase + wn + n * 16 + lr;
        float v = acc[m][n][r];
        size_t idx = (size_t)row * N + col;
        if (EPI == EPI_BF16) {
          Cb[idx] = f2bf(v);
        } else if (EPI == EPI_RESID) {
          Cf[idx] = v + resid[idx];
        } else if (EPI == EPI_GELU) {
          float g = 0.5f * v * (1.0f + erff(v * 0.70710678118f));
          Cb[idx] = f2bf(g);
        } else {
          Cb[idx] = f2bf(v);
        }
      }
    }
  }
}

// ---------------- Flash attention — paired q-tiles for causal load balance ----------------
// grid: (T/128 = 16 pairs, B*H). Block j handles q-tiles {31-j, j}: exactly 33
// kv-iterations per block -> uniform duration, no drain tail.
#define SCL2E 0.18033688011112042f   // 0.125 * log2(e)

__global__ __launch_bounds__(256) void attn_kernel(const short* __restrict__ qkv,
                                                   const short* __restrict__ vT,
                                                   short* __restrict__ o) {
  const int pj = blockIdx.x;           // 0..15
  const int bh = blockIdx.y;
  const int b = bh >> 4, h = bh & 15;
  const int w = threadIdx.x >> 6, lane = threadIdx.x & 63;
  const int lr = lane & 15, lkg = lane >> 4, lk = lkg * 8;
  const size_t rs = 3 * Dv;

  __shared__ short Ks[64][72];
  __shared__ short Vs[64][72];
  __shared__ short Ps[4][16][72];

  const short* kbase = qkv + (size_t)b * Tv * rs + Dv + h * 64;
  const short* vbase = vT + (size_t)bh * 64 * Tv;

  #pragma unroll 1
  for (int ph = 0; ph < 2; ++ph) {
    const int qt = ph ? pj : (Tv / 64 - 1 - pj);
    const int qbase = qt * 64;
    short8 qf0, qf1;
    {
      size_t qrow = (size_t)(b * Tv + qbase + w * 16 + lr) * rs + h * 64;
      qf0 = *(const short8*)(qkv + qrow + lk);
      qf1 = *(const short8*)(qkv + qrow + 32 + lk);
    }
    f32x4 oacc[4];
    #pragma unroll
    for (int n = 0; n < 4; n++) oacc[n] = (f32x4)0.0f;
    float mrow[4] = {-INFINITY, -INFINITY, -INFINITY, -INFINITY};
    float lrow4[4] = {0.f, 0.f, 0.f, 0.f};

    #pragma unroll 1
    for (int kv0 = 0; kv0 < qbase + 64; kv0 += 64) {
      #pragma unroll
      for (int i = 0; i < 2; i++) {
        int e = threadIdx.x + i * 256;
        int r = e >> 3, c = (e & 7) * 8;
        short8 kval = *(const short8*)(kbase + (size_t)(kv0 + r) * rs + c);
        *(short8*)(&Ks[r][c]) = kval;
        short8 vval = *(const short8*)(vbase + (size_t)r * Tv + kv0 + c);
        *(short8*)(&Vs[r][c]) = vval;
      }
      __syncthreads();
      f32x4 s[4];
      __builtin_amdgcn_s_setprio(1);
      #pragma unroll
      for (int n = 0; n < 4; n++) {
        s[n] = (f32x4)0.0f;
        short8 kf0 = *(const short8*)(&Ks[n * 16 + lr][lk]);
        short8 kf1 = *(const short8*)(&Ks[n * 16 + lr][32 + lk]);
        s[n] = __builtin_amdgcn_mfma_f32_16x16x32_bf16(qf0, kf0, s[n], 0, 0, 0);
        s[n] = __builtin_amdgcn_mfma_f32_16x16x32_bf16(qf1, kf1, s[n], 0, 0, 0);
      }
      __builtin_amdgcn_s_setprio(0);
      if (kv0 < qbase) {
        #pragma unroll
        for (int n = 0; n < 4; n++)
          #pragma unroll
          for (int r = 0; r < 4; r++) s[n][r] *= SCL2E;
      } else {
        #pragma unroll
        for (int n = 0; n < 4; n++)
          #pragma unroll
          for (int r = 0; r < 4; r++) {
            int tq = qbase + w * 16 + lkg * 4 + r;
            int tk = kv0 + n * 16 + lr;
            s[n][r] = (tk > tq) ? -1e30f : s[n][r] * SCL2E;
          }
      }
      float scr[4];
      #pragma unroll
      for (int r = 0; r < 4; r++) {
        float m = fmaxf(fmaxf(s[0][r], s[1][r]), fmaxf(s[2][r], s[3][r]));
        #pragma unroll
        for (int off = 8; off; off >>= 1) m = fmaxf(m, __shfl_xor(m, off, 64));
        float mnew = fmaxf(mrow[r], m);
        float sc = exp2f(mrow[r] - mnew);
        float rsum = 0.f;
        #pragma unroll
        for (int n = 0; n < 4; n++) { float p = exp2f(s[n][r] - mnew); s[n][r] = p; rsum += p; }
        #pragma unroll
        for (int off = 8; off; off >>= 1) rsum += __shfl_xor(rsum, off, 64);
        lrow4[r] = lrow4[r] * sc + rsum;
        mrow[r] = mnew;
        scr[r] = sc;
      }
      #pragma unroll
      for (int n = 0; n < 4; n++)
        #pragma unroll
        for (int r = 0; r < 4; r++) Ps[w][lkg * 4 + r][n * 16 + lr] = f2bf(s[n][r]);
      #pragma unroll
      for (int n = 0; n < 4; n++)
        #pragma unroll
        for (int r = 0; r < 4; r++) oacc[n][r] *= scr[r];
      __syncthreads();
      __builtin_amdgcn_s_setprio(1);
      #pragma unroll
      for (int n2 = 0; n2 < 4; n2++) {
        short8 pf0 = *(const short8*)(&Ps[w][lr][lk]);
        short8 pf1 = *(const short8*)(&Ps[w][lr][32 + lk]);
        short8 vf0 = *(const short8*)(&Vs[n2 * 16 + lr][lk]);
        short8 vf1 = *(const short8*)(&Vs[n2 * 16 + lr][32 + lk]);
        oacc[n2] = __builtin_amdgcn_mfma_f32_16x16x32_bf16(pf0, vf0, oacc[n2], 0, 0, 0);
        oacc[n2] = __builtin_amdgcn_mfma_f32_16x16x32_bf16(pf1, vf1, oacc[n2], 0, 0, 0);
      }
      __builtin_amdgcn_s_setprio(0);
      __syncthreads();
    }
    float rinv[4];
    #pragma unroll
    for (int r = 0; r < 4; r++) rinv[r] = 1.0f / lrow4[r];
    #pragma unroll
    for (int n2 = 0; n2 < 4; n2++)
      #pragma unroll
      for (int r = 0; r < 4; r++) {
        int tq = qbase + w * 16 + lkg * 4 + r;
        float v = oacc[n2][r] * rinv[r];
        o[(size_t)(b * Tv + tq) * Dv + h * 64 + n2 * 16 + lr] = f2bf(v);
      }
  }
}

// ---------------- Router ----------------
__global__ __launch_bounds__(256) void router_kernel(const float* __restrict__ x2f,
                                                     const float* __restrict__ rw,
                                                     int* __restrict__ topi,
                                                     float* __restrict__ topp) {
  int w = threadIdx.x >> 6, lane = threadIdx.x & 63;
  int t = blockIdx.x * 4 + w;
  const float* row = x2f + (size_t)t * Dv;
  float acc[8];
  #pragma unroll
  for (int e = 0; e < 8; e++) acc[e] = 0.f;
  for (int i = 0; i < 16; i++) {
    int d = lane + i * 64;
    float xv = row[d];
    const float* rwp = rw + (size_t)d * 8;
    #pragma unroll
    for (int e = 0; e < 8; e++) acc[e] += xv * rwp[e];
  }
  #pragma unroll
  for (int e = 0; e < 8; e++) acc[e] = wredsum(acc[e]);
  if (lane == 0) {
    float mx = acc[0];
    #pragma unroll
    for (int e = 1; e < 8; e++) mx = fmaxf(mx, acc[e]);
    float p[8]; float se = 0.f;
    #pragma unroll
    for (int e = 0; e < 8; e++) { p[e] = expf(acc[e] - mx); se += p[e]; }
    #pragma unroll
    for (int e = 0; e < 8; e++) p[e] /= se;
    int i1 = 0; float p1 = p[0];
    #pragma unroll
    for (int e = 1; e < 8; e++) if (p[e] > p1) { p1 = p[e]; i1 = e; }
    float pm = p[i1]; p[i1] = -1.f;
    int i2 = 0; float p2 = p[0];
    #pragma unroll
    for (int e = 1; e < 8; e++) if (p[e] > p2) { p2 = p[e]; i2 = e; }
    float sum = pm + p2;
    topi[t * 2] = i1; topi[t * 2 + 1] = i2;
    topp[t * 2] = pm / sum; topp[t * 2 + 1] = p2 / sum;
  }
}

// ---------------- bucket build (128-row tiles) ----------------
__global__ void bucket_count(const int* __restrict__ topi, int* __restrict__ offsets,
                             int* __restrict__ cursor) {
  __shared__ int cnt[8];
  if (threadIdx.x < 8) { cnt[threadIdx.x] = 0; cursor[threadIdx.x] = 0; }
  __syncthreads();
  for (int i = threadIdx.x; i < NT * 2; i += 256) atomicAdd(&cnt[topi[i]], 1);
  __syncthreads();
  if (threadIdx.x == 0) {
    int s = 0;
    for (int e = 0; e < 8; e++) { offsets[e] = s; s += cnt[e]; }
    offsets[8] = s;
  }
}
__global__ void bucket_scatter(const int* __restrict__ topi, const int* __restrict__ offsets,
                               int* __restrict__ cursor, int* __restrict__ perm,
                               int* __restrict__ row_of) {
  int i = blockIdx.x * 256 + threadIdx.x;
  if (i >= NT * 2) return;
  int e = topi[i];
  int slot = atomicAdd(&cursor[e], 1);
  int r = offsets[e] + slot;
  perm[r] = i >> 1;
  row_of[i] = r;
}
__global__ void tile_build(const int* __restrict__ offsets, int* __restrict__ tiles) {
  if (threadIdx.x == 0 && blockIdx.x == 0) {
    int nt = 0;
    for (int e = 0; e < 8; e++) {
      int r0 = offsets[e], r1 = offsets[e + 1];
      for (int m = r0; m < r1; m += 128) {
        tiles[1 + nt * 3] = e; tiles[2 + nt * 3] = m; tiles[3 + nt * 3] = r1; nt++;
      }
    }
    tiles[0] = nt;
  }
}

// ---------------- final ----------------
__global__ __launch_bounds__(256) void final_kernel(float* __restrict__ out,
                                                    const short* __restrict__ eout,
                                                    const int* __restrict__ row_of,
                                                    const float* __restrict__ topp) {
  int t = blockIdx.x; int tid = threadIdx.x;
  int r0 = row_of[t * 2], r1 = row_of[t * 2 + 1];
  float p0 = topp[t * 2], p1 = topp[t * 2 + 1];
  #pragma unroll
  for (int i = 0; i < 4; i++) {
    int d = tid + i * 256;
    out[(size_t)t * Dv + d] += p0 * bf2f(eout[(size_t)r0 * Dv + d])
                             + p1 * bf2f(eout[(size_t)r1 * Dv + d]);
  }
}

extern "C" void kernel_launch(void* const* d_in, const int* in_sizes, int n_in,
                              void* d_out, int out_size, void* d_ws, size_t ws_size,
                              hipStream_t stream) {
  const float* x        = (const float*)d_in[0];
  const float* ln1_w    = (const float*)d_in[1];
  const float* wqkv     = (const float*)d_in[2];
  const float* wproj    = (const float*)d_in[3];
  const float* ln2_w    = (const float*)d_in[4];
  const float* router_w = (const float*)d_in[5];
  const float* w1       = (const float*)d_in[6];
  const float* w2       = (const float*)d_in[7];
  float* out = (float*)d_out;
  char* ws = (char*)d_ws;

  size_t off = 0;
  short* wqkvT  = (short*)(ws + off); off += (size_t)3 * Dv * Dv * 2;
  short* wprojT = (short*)(ws + off); off += (size_t)Dv * Dv * 2;
  short* w1T    = (short*)(ws + off); off += (size_t)Ev * Dv * Fv * 2;
  short* w2T    = (short*)(ws + off); off += (size_t)Ev * Fv * Dv * 2;
  char* reg1 = ws + off; off += (size_t)NT * Dv * 2;
  short* hln1 = (short*)reg1;
  short* ob   = (short*)reg1;
  short* x2b  = (short*)reg1;
  char* reg2 = ws + off; off += (size_t)NT * 3 * Dv * 2;
  short* qkvb = (short*)reg2;
  float* xres = (float*)reg2;
  char* reg3 = ws + off; off += (size_t)NT * 2 * Fv * 2;
  short* vT = (short*)reg3;
  short* Hb = (short*)reg3;
  short* eout = (short*)(ws + off); off += (size_t)NT * 2 * Dv * 2;
  int*   topi = (int*)(ws + off);   off += NT * 2 * 4;
  float* topp = (float*)(ws + off); off += NT * 2 * 4;
  int*   offs = (int*)(ws + off);   off += 64;
  int*   cur  = (int*)(ws + off);   off += 64;
  int*   perm = (int*)(ws + off);   off += NT * 2 * 4;
  int*   rowof= (int*)(ws + off);   off += NT * 2 * 4;
  int*   tiles= (int*)(ws + off);   off += 1024;

  // 0. pre-transpose + convert weights to bf16 [N][K]
  transpose_cvt<<<dim3(Dv / 64, 3 * Dv / 64, 1), 256, 0, stream>>>(wqkv, wqkvT, Dv, 3 * Dv);
  transpose_cvt<<<dim3(Dv / 64, Dv / 64, 1), 256, 0, stream>>>(wproj, wprojT, Dv, Dv);
  transpose_cvt<<<dim3(Dv / 64, Fv / 64, Ev), 256, 0, stream>>>(w1, w1T, Dv, Fv);
  transpose_cvt<<<dim3(Fv / 64, Dv / 64, Ev), 256, 0, stream>>>(w2, w2T, Fv, Dv);

  // 1. LN1 -> bf16
  ln_kernel<<<NT, 256, 0, stream>>>(x, ln1_w, nullptr, hln1);
  // 2. QKV  (32x24 = 768 blocks, %8==0)
  gemm_lds<EPI_BF16, false, false, Dv><<<dim3(NT / 128, 3 * Dv / 128), 256, 0, stream>>>(
      hln1, wqkvT, qkvb, nullptr, nullptr, nullptr, nullptr, NT, 3 * Dv);
  // 2.5 V pre-transpose
  vtrans_kernel<<<dim3(Tv / 64, Bv * Hv), 256, 0, stream>>>(qkvb, vT);
  // 3. attention — paired q-tiles, 512 uniform blocks
  attn_kernel<<<dim3(Tv / 128, Bv * Hv), 256, 0, stream>>>(qkvb, vT, ob);
  // 4. xres = x + o @ wproj  (32x8 = 256 blocks)
  gemm_lds<EPI_RESID, false, false, Dv><<<dim3(NT / 128, Dv / 128), 256, 0, stream>>>(
      ob, wprojT, nullptr, xres, x, nullptr, nullptr, NT, Dv);
  // 5. LN2 -> d_out (f32) + bf16 copy
  ln_kernel<<<NT, 256, 0, stream>>>(xres, ln2_w, out, x2b);
  // 6. router
  router_kernel<<<NT / 4, 256, 0, stream>>>(out, router_w, topi, topp);
  // 7. buckets (128-row tiles)
  bucket_count<<<1, 256, 0, stream>>>(topi, offs, cur);
  bucket_scatter<<<NT * 2 / 256, 256, 0, stream>>>(topi, offs, cur, perm, rowof);
  tile_build<<<1, 1, 0, stream>>>(offs, tiles);
  // 8. H = gelu(gather(x2b) @ w1[e])   (72x32 = 2304 blocks, %8==0)
  gemm_lds<EPI_GELU, true, true, Dv><<<dim3(MAXTILES, Fv / 128), 256, 0, stream>>>(
      x2b, w1T, Hb, nullptr, nullptr, perm, tiles, 0, Fv);
  // 9. eout = H @ w2[e]   (72x8 = 576 blocks, %8==0)
  gemm_lds<EPI_BF16, true, false, Fv><<<dim3(MAXTILES, Dv / 128), 256, 0, stream>>>(
      Hb, w2T, eout, nullptr, nullptr, nullptr, tiles, 0, Dv);
  // 10. out += p0*eout[r0] + p1*eout[r1]
  final_kernel<<<NT, 256, 0, stream>>>(out, eout, rowof, topp);
}